// Round 9
// baseline (151.501 us; speedup 1.0000x reference)
//
#include <hip/hip_runtime.h>
#include <hip/hip_bf16.h>
#include <math.h>

#define FRAME_LEN 882
#define FRAME_HOP 441
#define NFFT 2048
#define NFRAMES 999
#define NBATCH 16
#define NMEL 60
#define WAVE_LEN 441000
#define PRE_EMPH 0.97f
#define EPS 1e-10f
#define NROWS (NBATCH * NFRAMES)     // 15984 = 999 panels x 16 rows
#define NPANEL 999
#define KPAD 1056                    // 33*32
#define NKC 33
#define PANEL_ELEMS (NKC * 512)      // 16896 bf16 per panel (frag-linear)
#define STG_STRIDE 1064              // staging row stride in shorts (1056 + 8 pad)
#define PI_F 3.14159265358979323846f

// LDS float2 index padding for the FFT buffer
#define PADI(i) ((i) + ((i) >> 4))

// Frag-linear offset of (row m in panel, bin k) — used by filtconv only now.
__device__ __forceinline__ int frag_off(int m, int k) {
  return ((k >> 5) * 512) | (((k >> 3) & 3) * 128) | (m * 8) | (k & 7);
}

// Packed complex type
typedef float vf2 __attribute__((ext_vector_type(2)));
__device__ __forceinline__ vf2 mkv(float x, float y){ vf2 r; r.x = x; r.y = y; return r; }
__device__ __forceinline__ vf2 cmul(vf2 a, vf2 b){ return a.xx * b + mkv(-a.y, a.y) * b.yx; }
__device__ __forceinline__ vf2 rotni(vf2 z){ return mkv(z.y, -z.x); }  // z * (-i)

// Three consecutive DIF radix-2 stages (halves 4S,2S,S) in registers.
__device__ __forceinline__ void dif_group8(vf2* x, vf2 t1) {
  const vf2 C41 = mkv(0.7071067812f, -0.7071067812f);
  vf2 w0 = t1, w1 = cmul(t1, C41), w2 = rotni(w0), w3 = rotni(w1);
  vf2 u, v;
  u=x[0]; v=x[4]; x[0]=u+v; x[4]=cmul(u-v, w0);
  u=x[1]; v=x[5]; x[1]=u+v; x[5]=cmul(u-v, w1);
  u=x[2]; v=x[6]; x[2]=u+v; x[6]=cmul(u-v, w2);
  u=x[3]; v=x[7]; x[3]=u+v; x[7]=cmul(u-v, w3);
  vf2 t2 = cmul(t1, t1), t2r = rotni(t2);
  u=x[0]; v=x[2]; x[0]=u+v; x[2]=cmul(u-v, t2);
  u=x[1]; v=x[3]; x[1]=u+v; x[3]=cmul(u-v, t2r);
  u=x[4]; v=x[6]; x[4]=u+v; x[6]=cmul(u-v, t2);
  u=x[5]; v=x[7]; x[5]=u+v; x[7]=cmul(u-v, t2r);
  vf2 t4 = cmul(t2, t2);
  u=x[0]; v=x[1]; x[0]=u+v; x[1]=cmul(u-v, t4);
  u=x[2]; v=x[3]; x[2]=u+v; x[3]=cmul(u-v, t4);
  u=x[4]; v=x[5]; x[4]=u+v; x[5]=cmul(u-v, t4);
  u=x[6]; v=x[7]; x[6]=u+v; x[7]=cmul(u-v, t4);
}

__device__ __forceinline__ void dif_radix4(vf2* x) {
  vf2 y0 = x[0] + x[2];
  vf2 y2 = x[0] - x[2];
  vf2 y1 = x[1] + x[3];
  vf2 y3 = rotni(x[1] - x[3]);
  x[0] = y0 + y1; x[1] = y0 - y1;
  x[2] = y2 + y3; x[3] = y2 - y3;
}

__device__ __forceinline__ unsigned bf16bits(float v) {
  union { float f; unsigned u; } c; c.f = v;
  unsigned lsb = (c.u >> 16) & 1;
  return ((c.u + 0x7fff + lsb) >> 16) & 0xffff;   // RNE, matches __float2bfloat16 for finite
}

// Kernel 1: one block = one 16-frame panel (999 blocks). 8 sequential
// frame-pair FFT passes; power goes to a linear LDS staging buffer; final
// copy-out emits the complete panel in frag order with fully-coalesced
// uint4 global stores. All sincos hoisted out of the pass loop.
__global__ __launch_bounds__(256) void fft_pow_kernel(
    const float* __restrict__ wav, __hip_bfloat16* __restrict__ powrF)
{
  __shared__ vf2 lds[NFFT + (NFFT >> 4)];        // 17408 B
  __shared__ unsigned short stage[16 * STG_STRIDE]; // 34048 B ; row m = frame m of panel
  const int t = threadIdx.x;
  const int p = blockIdx.x;

  // ---- hoisted twiddles / window basis ----
  vf2 win0, wstep, tw0, tw1, tw2;
  {
    float s, c;
    __sincosf(6.283185307179586f * (float)t / 881.0f, &s, &c); win0 = mkv(c, s);
    __sincosf(6.283185307179586f * 256.0f / 881.0f, &s, &c);   wstep = mkv(c, s);
    __sincosf(-PI_F * (float)t / 1024.0f, &s, &c);             tw0 = mkv(c, s);
    __sincosf(-PI_F * (float)(t & 31) / 128.0f, &s, &c);       tw1 = mkv(c, s);
    const int r = t & 3;
    float tc = (r == 0) ? 1.0f : (r == 1) ? 0.980785280f : (r == 2) ? 0.923879533f : 0.831469612f;
    float ts = (r == 0) ? 0.0f : (r == 1) ? -0.195090322f : (r == 2) ? -0.382683432f : -0.555570233f;
    tw2 = mkv(tc, ts);
  }
  // hoisted bit-reversed pair indices for the power phase (f = 2u, 2u+1; u = t + 256c)
  int jz[2], jy[2];
#pragma unroll
  for (int c = 0; c < 2; ++c) {
    int u2 = 2 * (t + 256 * c);
    jz[c] = PADI((int)(__brev((unsigned)u2) >> 21));                       // brev(2u); brev(2u+1) = +1024 pre-PADI
    jy[c] = PADI((int)(__brev((unsigned)((NFFT - u2) & (NFFT - 1))) >> 21));
  }

  for (int i = 0; i < 8; ++i) {
    const int rA = 16 * p + 2 * i, rB = rA + 1;
    const int bA = rA / NFRAMES, tA = rA - bA * NFRAMES;
    const int bB = rB / NFRAMES, tB = rB - bB * NFRAMES;
    const float* wA = wav + (size_t)bA * WAVE_LEN;
    const float* wB = wav + (size_t)bB * WAVE_LEN;
    const int sA = tA * FRAME_HOP, sB = tB * FRAME_HOP;

    vf2 x[8];
    // ---- load + pre-emphasis + Hamming ----
    {
      vf2 cur = win0;
#pragma unroll
      for (int k = 0; k < 4; ++k) {
        int idx = k * 256 + t;
        float v1 = 0.f, v2 = 0.f;
        if (idx < FRAME_LEN) {
          float win = 0.54f - 0.46f * cur.x;
          int s = sA + idx;
          float e1 = (s > 0) ? (wA[s] - PRE_EMPH * wA[s - 1]) : wA[s];
          v1 = e1 * win;
          int ss = sB + idx;
          float e2 = (ss > 0) ? (wB[ss] - PRE_EMPH * wB[ss - 1]) : wB[ss];
          v2 = e2 * win;
        }
        x[k] = mkv(v1, v2);
        if (k < 3) cur = cmul(cur, wstep);
      }
#pragma unroll
      for (int k = 4; k < 8; ++k) x[k] = mkv(0.f, 0.f);
    }

    // ---- G0: halves 1024,512,256 (S=256, r=t) ----
    dif_group8(x, tw0);
#pragma unroll
    for (int k = 0; k < 8; ++k) lds[PADI(k * 256 + t)] = x[k];
    __syncthreads();

    // ---- G1: halves 128,64,32 (S=32) ----
    {
      const int q = t >> 5, r = t & 31;
#pragma unroll
      for (int k = 0; k < 8; ++k) x[k] = lds[PADI(q * 256 + k * 32 + r)];
      dif_group8(x, tw1);
      __syncthreads();
#pragma unroll
      for (int k = 0; k < 8; ++k) lds[PADI(q * 256 + k * 32 + r)] = x[k];
    }
    __syncthreads();

    // ---- G2: halves 16,8,4 (S=4) ----
    {
      const int q = t >> 2, r = t & 3;
#pragma unroll
      for (int k = 0; k < 8; ++k) x[k] = lds[PADI(q * 32 + k * 4 + r)];
      dif_group8(x, tw2);
      __syncthreads();
#pragma unroll
      for (int k = 0; k < 8; ++k) lds[PADI(q * 32 + k * 4 + r)] = x[k];
    }
    __syncthreads();

    // ---- G3: halves 2,1 ----
    {
      vf2 xa[4], xb[4];
#pragma unroll
      for (int j = 0; j < 4; ++j) {
        xa[j] = lds[PADI(4 * t + j)];
        xb[j] = lds[PADI(4 * (t + 256) + j)];
      }
      dif_radix4(xa);
      dif_radix4(xb);
      __syncthreads();
#pragma unroll
      for (int j = 0; j < 4; ++j) {
        lds[PADI(4 * t + j)] = xa[j];
        lds[PADI(4 * (t + 256) + j)] = xb[j];
      }
    }
    __syncthreads();

    // ---- power separation -> linear LDS staging (rows 2i, 2i+1) ----
    // f = 2u, 2u+1 packed as one uint per frame; conflict-free b32 writes.
    unsigned short* rowA = stage + (2 * i) * STG_STRIDE;
    unsigned short* rowB = rowA + STG_STRIDE;
#pragma unroll
    for (int c = 0; c < 2; ++c) {
      int u = t + 256 * c;
      vf2 z0 = lds[jz[c]];          // bin 2u
      vf2 y0 = lds[jy[c]];          // bin 2048-2u
      vf2 z1 = lds[PADI((jz[c] - (jz[c] >> 4) /*un-PAD*/))];  // placeholder avoided below
      // bin 2u+1 lives at brev(2u)+1024 (pre-PAD); recompute cleanly:
      int j1 = (int)(__brev((unsigned)(2 * u)) >> 21);
      vf2 z1b = lds[PADI(j1 + 1024)];
      int j2b = 2047 - j1;          // brev(2047-2u) = 2047 - brev(2u)
      vf2 y1b = lds[PADI(j2b)];
      // even bin
      float f1r = z0.x + y0.x, f1i = z0.y - y0.y;
      float f2r = z0.y + y0.y, f2i = y0.x - z0.x;
      float pA0 = 0.25f * (f1r * f1r + f1i * f1i);
      float pB0 = 0.25f * (f2r * f2r + f2i * f2i);
      // odd bin
      f1r = z1b.x + y1b.x; f1i = z1b.y - y1b.y;
      f2r = z1b.y + y1b.y; f2i = y1b.x - z1b.x;
      float pA1 = 0.25f * (f1r * f1r + f1i * f1i);
      float pB1 = 0.25f * (f2r * f2r + f2i * f2i);
      unsigned uA = bf16bits(pA0) | (bf16bits(pA1) << 16);
      unsigned uB = bf16bits(pB0) | (bf16bits(pB1) << 16);
      *(unsigned*)(rowA + 2 * u) = uA;
      *(unsigned*)(rowB + 2 * u) = uB;
    }
    // bins 1024..1055 (bin 1024 real, 1025.. zero pads): pairs u = 512 + t, t<16
    if (t < 16) {
      float pA0 = 0.f, pB0 = 0.f;
      if (t == 0) {
        vf2 z = lds[PADI(1)];       // brev(1024) = 1
        pA0 = z.x * z.x;
        pB0 = z.y * z.y;
      }
      unsigned uA = bf16bits(pA0);  // odd half = 0
      unsigned uB = bf16bits(pB0);
      *(unsigned*)(rowA + 1024 + 2 * t) = uA;
      *(unsigned*)(rowB + 1024 + 2 * t) = uB;
    }
    __syncthreads();   // fft lds reads done before next pass; staging visible at end
  }

  // ---- coalesced panel write-out: global uint4 g -> (kc=g>>6, sub=(g>>4)&3, m=g&15)
  uint4* g4 = (uint4*)(powrF + (size_t)p * PANEL_ELEMS);
#pragma unroll
  for (int c = 0; c < 9; ++c) {
    int g = c * 256 + t;
    if (c < 8 || t < 64) {         // 2112 uint4 total
      int kc = g >> 6, sub = (g >> 4) & 3, m = g & 15;
      const uint4* src = (const uint4*)(stage + m * STG_STRIDE + kc * 32 + sub * 8);
      g4[g] = *src;
    }
  }
}

// Kernel 0: filt (60x1025 f32) -> bf16 in FRAGMENT order, 4 panels of 16 mels.
__global__ __launch_bounds__(256) void filtconv_kernel(
    const float* __restrict__ filt, __hip_bfloat16* __restrict__ filtbF)
{
  const int mm = blockIdx.x;  // 0..63
  __hip_bfloat16* qp = filtbF + (size_t)(mm >> 4) * PANEL_ELEMS;
  const int m = mm & 15;
  for (int k = threadIdx.x; k < KPAD; k += 256) {
    float v = (mm < NMEL && k < 1025) ? filt[mm * 1025 + k] : 0.f;
    qp[frag_off(m, k)] = __float2bfloat16(v);
  }
}

// Kernel 2: mel GEMM, 2 row-panels per block (500 blocks): B fragments read
// once per wave serve TWO panels -> half the B L2 traffic, 3 loads / 2 MFMAs.
typedef __attribute__((ext_vector_type(8))) short short8x;
typedef __attribute__((ext_vector_type(4))) float float4x;

__global__ __launch_bounds__(256) void melgemm_kernel(
    const __hip_bfloat16* __restrict__ powrF,
    const __hip_bfloat16* __restrict__ filtbF,
    float* __restrict__ logmelT)
{
  const int wave = threadIdx.x >> 6, lane = threadIdx.x & 63;
  const int p0 = blockIdx.x * 2;
  const int p1 = p0 + 1;
  const bool has1 = (p1 < NPANEL);
  const int p1c = has1 ? p1 : p0;
  const __hip_bfloat16* pA0 = powrF + (size_t)p0 * PANEL_ELEMS + lane * 8;
  const __hip_bfloat16* pA1 = powrF + (size_t)p1c * PANEL_ELEMS + lane * 8;
  const __hip_bfloat16* pB  = filtbF + (size_t)wave * PANEL_ELEMS + lane * 8;

  float4x acc0 = {0.f, 0.f, 0.f, 0.f};
  float4x acc1 = {0.f, 0.f, 0.f, 0.f};
#pragma unroll 3
  for (int kc = 0; kc < NKC; ++kc) {
    short8x b  = *(const short8x*)(pB + kc * 512);
    short8x a0 = *(const short8x*)(pA0 + kc * 512);
    short8x a1 = *(const short8x*)(pA1 + kc * 512);
    acc0 = __builtin_amdgcn_mfma_f32_16x16x32_bf16(a0, b, acc0, 0, 0, 0);
    acc1 = __builtin_amdgcn_mfma_f32_16x16x32_bf16(a1, b, acc1, 0, 0, 0);
  }

  // C/D layout: col = lane&15 (mel), row = (lane>>4)*4 + reg (panel row)
  const int mel = wave * 16 + (lane & 15);
  const int rsub = (lane >> 4) * 4;
  if (mel < NMEL) {
#pragma unroll
    for (int reg = 0; reg < 4; ++reg) {
      int row0 = p0 * 16 + rsub + reg;
      logmelT[(size_t)mel * NROWS + row0] = __logf(acc0[reg] + EPS);
      if (has1) {
        int row1 = p1 * 16 + rsub + reg;
        logmelT[(size_t)mel * NROWS + row1] = __logf(acc1[reg] + EPS);
      }
    }
  }
}

// Kernel 3: stats on transposed logmel (unchanged from R8).
__global__ __launch_bounds__(256) void stats_kernel(
    const float* __restrict__ lmT, float* __restrict__ out)
{
  __shared__ float red[4];
  const int j   = blockIdx.x;   // 0..89
  const int b   = blockIdx.y;   // 0..15
  const int tid = threadIdx.x;
  const int base = b * NFRAMES;
  const float inv_sq2 = 0.7071067811865475f;
  const bool v3 = (tid < NFRAMES - 768);

  float f0, f1, f2, f3;
  if (j < 30) {
    const float* e = lmT + (size_t)(2 * j) * NROWS + base;
    const float* o = lmT + (size_t)(2 * j + 1) * NROWS + base;
    f0 = (e[tid]       + o[tid])       * inv_sq2;
    f1 = (e[tid + 256] + o[tid + 256]) * inv_sq2;
    f2 = (e[tid + 512] + o[tid + 512]) * inv_sq2;
    f3 = v3 ? (e[tid + 768] + o[tid + 768]) * inv_sq2 : 0.f;
  } else if (j < 60) {
    const int m = j - 30;
    const float* e = lmT + (size_t)(2 * m) * NROWS + base;
    const float* o = lmT + (size_t)(2 * m + 1) * NROWS + base;
    auto dl = [&](int t) -> float {
      int tp = (t + 1 > NFRAMES - 1) ? (NFRAMES - 1) : (t + 1);
      int tm = (t - 1 < 0) ? 0 : (t - 1);
      return ((e[tp] + o[tp]) - (e[tm] + o[tm])) * inv_sq2;
    };
    f0 = dl(tid);
    f1 = dl(tid + 256);
    f2 = dl(tid + 512);
    f3 = v3 ? dl(tid + 768) : 0.f;
  } else {
    const int m = j - 60;
    const float* e = lmT + (size_t)(2 * m) * NROWS + base;
    const float* o = lmT + (size_t)(2 * m + 1) * NROWS + base;
    f0 = (e[tid]       - o[tid])       * inv_sq2;
    f1 = (e[tid + 256] - o[tid + 256]) * inv_sq2;
    f2 = (e[tid + 512] - o[tid + 512]) * inv_sq2;
    f3 = v3 ? (e[tid + 768] - o[tid + 768]) * inv_sq2 : 0.f;
  }

  float s = f0 + f1 + f2 + f3;
  for (int o2 = 32; o2 > 0; o2 >>= 1) s += __shfl_xor(s, o2, 64);
  if ((tid & 63) == 0) red[tid >> 6] = s;
  __syncthreads();
  float mean = (red[0] + red[1] + red[2] + red[3]) / (float)NFRAMES;
  __syncthreads();

  float d0 = f0 - mean, d1 = f1 - mean, d2 = f2 - mean;
  float d3 = v3 ? (f3 - mean) : 0.f;
  float s2 = d0 * d0 + d1 * d1 + d2 * d2 + d3 * d3;
  for (int o2 = 32; o2 > 0; o2 >>= 1) s2 += __shfl_xor(s2, o2, 64);
  if ((tid & 63) == 0) red[tid >> 6] = s2;
  __syncthreads();
  float var = (red[0] + red[1] + red[2] + red[3]) / (float)(NFRAMES - 1);

  if (tid == 0) {
    out[b * 180 + j]      = mean;
    out[b * 180 + 90 + j] = sqrtf(var);
  }
}

extern "C" void kernel_launch(void* const* d_in, const int* in_sizes, int n_in,
                              void* d_out, int out_size, void* d_ws, size_t ws_size,
                              hipStream_t stream) {
  const float* wav  = (const float*)d_in[0];   // (16, 441000) f32
  const float* filt = (const float*)d_in[1];   // (60, 1025) f32
  float* out = (float*)d_out;                  // (16, 180) f32

  // ws: powrF bf16 [999 panels][16896], filtbF bf16 [4][16896], logmelT f32 [60][NROWS]
  unsigned char* ws = (unsigned char*)d_ws;
  __hip_bfloat16* powrF  = (__hip_bfloat16*)(ws);
  size_t off = (size_t)NPANEL * PANEL_ELEMS * 2;              // 33,758,208
  __hip_bfloat16* filtbF = (__hip_bfloat16*)(ws + off);
  off += (size_t)4 * PANEL_ELEMS * 2;                         // +135,168
  float* logmelT = (float*)(ws + off);                        // +3,836,160 => ~37.7 MB

  filtconv_kernel<<<64, 256, 0, stream>>>(filt, filtbF);
  fft_pow_kernel<<<NPANEL, 256, 0, stream>>>(wav, powrF);
  melgemm_kernel<<<(NPANEL + 1) / 2, 256, 0, stream>>>(powrF, filtbF, logmelT);
  stats_kernel<<<dim3(90, NBATCH), 256, 0, stream>>>(logmelT, out);
}

// Round 10
// 119.675 us; speedup vs baseline: 1.2659x; 1.2659x over previous
//
#include <hip/hip_runtime.h>
#include <hip/hip_bf16.h>
#include <math.h>

#define FRAME_LEN 882
#define FRAME_HOP 441
#define NFFT 2048
#define NFRAMES 999
#define NBATCH 16
#define NMEL 60
#define WAVE_LEN 441000
#define PRE_EMPH 0.97f
#define EPS 1e-10f
#define NROWS (NBATCH * NFRAMES)     // 15984 = 999 panels x 16 rows
#define NPANEL 999
#define KPAD 1056                    // 33*32
#define NKC 33
#define PANEL_ELEMS (NKC * 512)      // 16896 bf16 per panel (frag-linear)
#define PI_F 3.14159265358979323846f

// LDS float2 index padding: +1 float2 per 16 -> breaks power-of-2 stride conflicts
#define PADI(i) ((i) + ((i) >> 4))

// Frag-linear offset of (row m in panel, bin k):
// reader lane l reads elems [kc*512 + l*8, +8) <-> (m=l&15, k=kc*32+(l>>4)*8+j)
__device__ __forceinline__ int frag_off(int m, int k) {
  return ((k >> 5) * 512) | (((k >> 3) & 3) * 128) | (m * 8) | (k & 7);
}

// Packed complex type
typedef float vf2 __attribute__((ext_vector_type(2)));
__device__ __forceinline__ vf2 mkv(float x, float y){ vf2 r; r.x = x; r.y = y; return r; }
__device__ __forceinline__ vf2 cmul(vf2 a, vf2 b){ return a.xx * b + mkv(-a.y, a.y) * b.yx; }
__device__ __forceinline__ vf2 rotni(vf2 z){ return mkv(z.y, -z.x); }  // z * (-i)

// Three consecutive DIF radix-2 stages (halves 4S,2S,S) in registers.
// Thread owns e_k = q*8S + k*S + r. ALL twiddles derive from t1 = e^{-i*pi*r/(4S)}.
__device__ __forceinline__ void dif_group8(vf2* x, vf2 t1) {
  const vf2 C41 = mkv(0.7071067812f, -0.7071067812f);
  vf2 w0 = t1, w1 = cmul(t1, C41), w2 = rotni(w0), w3 = rotni(w1);
  vf2 u, v;
  u=x[0]; v=x[4]; x[0]=u+v; x[4]=cmul(u-v, w0);
  u=x[1]; v=x[5]; x[1]=u+v; x[5]=cmul(u-v, w1);
  u=x[2]; v=x[6]; x[2]=u+v; x[6]=cmul(u-v, w2);
  u=x[3]; v=x[7]; x[3]=u+v; x[7]=cmul(u-v, w3);
  vf2 t2 = cmul(t1, t1), t2r = rotni(t2);
  u=x[0]; v=x[2]; x[0]=u+v; x[2]=cmul(u-v, t2);
  u=x[1]; v=x[3]; x[1]=u+v; x[3]=cmul(u-v, t2r);
  u=x[4]; v=x[6]; x[4]=u+v; x[6]=cmul(u-v, t2);
  u=x[5]; v=x[7]; x[5]=u+v; x[7]=cmul(u-v, t2r);
  vf2 t4 = cmul(t2, t2);
  u=x[0]; v=x[1]; x[0]=u+v; x[1]=cmul(u-v, t4);
  u=x[2]; v=x[3]; x[2]=u+v; x[3]=cmul(u-v, t4);
  u=x[4]; v=x[5]; x[4]=u+v; x[5]=cmul(u-v, t4);
  u=x[6]; v=x[7]; x[6]=u+v; x[7]=cmul(u-v, t4);
}

// Final two DIF stages (halves 2,1) on 4 consecutive elements: twiddles 1, -i.
__device__ __forceinline__ void dif_radix4(vf2* x) {
  vf2 y0 = x[0] + x[2];
  vf2 y2 = x[0] - x[2];
  vf2 y1 = x[1] + x[3];
  vf2 y3 = rotni(x[1] - x[3]);
  x[0] = y0 + y1; x[1] = y0 - y1;
  x[2] = y2 + y3; x[3] = y2 - y3;
}

// Kernel 1 (merged): blocks [0,8000) = R8's fft_pow verbatim (one frame-pair,
// 17.4 KB LDS, frag-order power stores); blocks [8000,8064) = filter->bf16
// fragment conversion, hidden under the fft dispatch instead of serialized.
__global__ __launch_bounds__(256) void fft_pow_kernel(
    const float* __restrict__ wav, const float* __restrict__ filt,
    __hip_bfloat16* __restrict__ powrF, __hip_bfloat16* __restrict__ filtbF)
{
  __shared__ vf2 lds[NFFT + (NFFT >> 4)];   // 17408 B
  const int id = blockIdx.x;

  if (id >= 8000) {
    // ---- filter conversion branch (64 blocks) ----
    const int mm = id - 8000;  // 0..63
    __hip_bfloat16* qp = filtbF + (size_t)(mm >> 4) * PANEL_ELEMS;
    const int m = mm & 15;
    for (int k = threadIdx.x; k < KPAD; k += 256) {
      float v = (mm < NMEL && k < 1025) ? filt[mm * 1025 + k] : 0.f;
      qp[frag_off(m, k)] = __float2bfloat16(v);
    }
    return;
  }

  const int t  = threadIdx.x;
  const int b  = id & 15;
  const int t0 = 2 * (id >> 4), t1f = t0 + 1;
  const bool has1 = (t1f < NFRAMES);
  const float* w = wav + (size_t)b * WAVE_LEN;
  const int s0 = t0 * FRAME_HOP;
  int s1 = t1f * FRAME_HOP;
  if (s1 > WAVE_LEN - FRAME_LEN) s1 = WAVE_LEN - FRAME_LEN;

  vf2 x[8];
  // ---- load + pre-emphasis + Hamming (cos via one sincos + recurrence) ----
  {
    float sB, cB, sD, cD;
    __sincosf(6.283185307179586f * (float)t / 881.0f, &sB, &cB);
    __sincosf(6.283185307179586f * 256.0f / 881.0f, &sD, &cD);
    vf2 cur  = mkv(cB, sB);
    vf2 step = mkv(cD, sD);
#pragma unroll
    for (int k = 0; k < 8; ++k) {
      int i = k * 256 + t;
      float v1 = 0.f, v2 = 0.f;
      if (i < FRAME_LEN) {
        float win = 0.54f - 0.46f * cur.x;
        int s = s0 + i;
        float e1 = (s > 0) ? (w[s] - PRE_EMPH * w[s - 1]) : w[s];
        v1 = e1 * win;
        int ss = s1 + i;                    // ss >= 441 > 0 always
        v2 = (w[ss] - PRE_EMPH * w[ss - 1]) * win;
      }
      x[k] = mkv(v1, v2);
      cur = cmul(cur, step);
    }
  }

  // ---- G0: halves 1024,512,256 (S=256, r=t): t1 = e^{-i*pi*t/1024}
  {
    float sA, cA;
    __sincosf(-PI_F * (float)t / 1024.0f, &sA, &cA);
    dif_group8(x, mkv(cA, sA));
  }
#pragma unroll
  for (int k = 0; k < 8; ++k) lds[PADI(k * 256 + t)] = x[k];
  __syncthreads();

  // ---- G1: halves 128,64,32 (S=32): t1 = e^{-i*pi*r/128}, r = t&31
  {
    const int q = t >> 5, r = t & 31;
#pragma unroll
    for (int k = 0; k < 8; ++k) x[k] = lds[PADI(q * 256 + k * 32 + r)];
    float sA, cA;
    __sincosf(-PI_F * (float)r / 128.0f, &sA, &cA);
    dif_group8(x, mkv(cA, sA));
    __syncthreads();
#pragma unroll
    for (int k = 0; k < 8; ++k) lds[PADI(q * 256 + k * 32 + r)] = x[k];
  }
  __syncthreads();

  // ---- G2: halves 16,8,4 (S=4): t1 = e^{-i*pi*r/16}, r = t&3 -> const table
  {
    const int q = t >> 2, r = t & 3;
#pragma unroll
    for (int k = 0; k < 8; ++k) x[k] = lds[PADI(q * 32 + k * 4 + r)];
    float tc = (r == 0) ? 1.0f : (r == 1) ? 0.980785280f : (r == 2) ? 0.923879533f : 0.831469612f;
    float ts = (r == 0) ? 0.0f : (r == 1) ? -0.195090322f : (r == 2) ? -0.382683432f : -0.555570233f;
    dif_group8(x, mkv(tc, ts));
    __syncthreads();
#pragma unroll
    for (int k = 0; k < 8; ++k) lds[PADI(q * 32 + k * 4 + r)] = x[k];
  }
  __syncthreads();

  // ---- G3: halves 2,1 — two radix-4 groups of 4 consecutive elements
  {
    vf2 xa[4], xb[4];
#pragma unroll
    for (int j = 0; j < 4; ++j) {
      xa[j] = lds[PADI(4 * t + j)];
      xb[j] = lds[PADI(4 * (t + 256) + j)];
    }
    dif_radix4(xa);
    dif_radix4(xb);
    __syncthreads();
#pragma unroll
    for (int j = 0; j < 4; ++j) {
      lds[PADI(4 * t + j)] = xa[j];
      lds[PADI(4 * (t + 256) + j)] = xb[j];
    }
  }
  __syncthreads();

  // ---- power separation + bf16 store in FRAGMENT order ----
  const int r0g = b * NFRAMES + t0;
  const int r1g = r0g + 1;
  __hip_bfloat16* q0 = powrF + (size_t)(r0g >> 4) * PANEL_ELEMS;
  const int m0 = r0g & 15;
  __hip_bfloat16* q1 = powrF + (size_t)(r1g >> 4) * PANEL_ELEMS;
  const int m1 = r1g & 15;
#pragma unroll
  for (int c = 0; c < 4; ++c) {
    int f = t + 256 * c;
    int j1 = (int)(__brev((unsigned)f) >> 21);
    int j2 = (int)(__brev((unsigned)((NFFT - f) & (NFFT - 1))) >> 21);
    vf2 z = lds[PADI(j1)];
    vf2 y = lds[PADI(j2)];
    float f1r = z.x + y.x, f1i = z.y - y.y;
    float f2r = z.y + y.y, f2i = y.x - z.x;
    float pw1 = 0.25f * (f1r * f1r + f1i * f1i);
    float pw2 = 0.25f * (f2r * f2r + f2i * f2i);
    q0[frag_off(m0, f)] = __float2bfloat16(pw1);
    if (has1) q1[frag_off(m1, f)] = __float2bfloat16(pw2);
  }
  if (t == 0) {
    vf2 z = lds[PADI(1)];            // brev(1024) = 1; bin 1024 self-conjugate
    q0[frag_off(m0, 1024)] = __float2bfloat16(z.x * z.x);
    if (has1) q1[frag_off(m1, 1024)] = __float2bfloat16(z.y * z.y);
  }
  // zero the K pads (1025..KPAD-1)
  if (t < KPAD - 1025) {
    int f = 1025 + t;
    q0[frag_off(m0, f)] = __float2bfloat16(0.f);
    if (has1) q1[frag_off(m1, f)] = __float2bfloat16(0.f);
  }
}

// Kernel 2: mel GEMM, 2 row-panels per block (500 blocks): each B fragment
// read serves TWO panels -> half the B L2 traffic, 3 loads / 2 MFMAs.
// (Correctness of this variant verified in R9.)
typedef __attribute__((ext_vector_type(8))) short short8x;
typedef __attribute__((ext_vector_type(4))) float float4x;

__global__ __launch_bounds__(256) void melgemm_kernel(
    const __hip_bfloat16* __restrict__ powrF,
    const __hip_bfloat16* __restrict__ filtbF,
    float* __restrict__ logmelT)
{
  const int wave = threadIdx.x >> 6, lane = threadIdx.x & 63;
  const int p0 = blockIdx.x * 2;
  const int p1 = p0 + 1;
  const bool has1 = (p1 < NPANEL);
  const int p1c = has1 ? p1 : p0;
  const __hip_bfloat16* pA0 = powrF + (size_t)p0 * PANEL_ELEMS + lane * 8;
  const __hip_bfloat16* pA1 = powrF + (size_t)p1c * PANEL_ELEMS + lane * 8;
  const __hip_bfloat16* pB  = filtbF + (size_t)wave * PANEL_ELEMS + lane * 8;

  float4x acc0 = {0.f, 0.f, 0.f, 0.f};
  float4x acc1 = {0.f, 0.f, 0.f, 0.f};
#pragma unroll 3
  for (int kc = 0; kc < NKC; ++kc) {
    short8x b  = *(const short8x*)(pB + kc * 512);
    short8x a0 = *(const short8x*)(pA0 + kc * 512);
    short8x a1 = *(const short8x*)(pA1 + kc * 512);
    acc0 = __builtin_amdgcn_mfma_f32_16x16x32_bf16(a0, b, acc0, 0, 0, 0);
    acc1 = __builtin_amdgcn_mfma_f32_16x16x32_bf16(a1, b, acc1, 0, 0, 0);
  }

  // C/D layout: col = lane&15 (mel), row = (lane>>4)*4 + reg (panel row)
  const int mel = wave * 16 + (lane & 15);
  const int rsub = (lane >> 4) * 4;
  if (mel < NMEL) {
#pragma unroll
    for (int reg = 0; reg < 4; ++reg) {
      int row0 = p0 * 16 + rsub + reg;
      logmelT[(size_t)mel * NROWS + row0] = __logf(acc0[reg] + EPS);
      if (has1) {
        int row1 = p1 * 16 + rsub + reg;
        logmelT[(size_t)mel * NROWS + row1] = __logf(acc1[reg] + EPS);
      }
    }
  }
}

// Kernel 3: stats on transposed logmel (unchanged from R8).
__global__ __launch_bounds__(256) void stats_kernel(
    const float* __restrict__ lmT, float* __restrict__ out)
{
  __shared__ float red[4];
  const int j   = blockIdx.x;   // 0..89
  const int b   = blockIdx.y;   // 0..15
  const int tid = threadIdx.x;
  const int base = b * NFRAMES;
  const float inv_sq2 = 0.7071067811865475f;
  const bool v3 = (tid < NFRAMES - 768);

  float f0, f1, f2, f3;
  if (j < 30) {
    const float* e = lmT + (size_t)(2 * j) * NROWS + base;
    const float* o = lmT + (size_t)(2 * j + 1) * NROWS + base;
    f0 = (e[tid]       + o[tid])       * inv_sq2;
    f1 = (e[tid + 256] + o[tid + 256]) * inv_sq2;
    f2 = (e[tid + 512] + o[tid + 512]) * inv_sq2;
    f3 = v3 ? (e[tid + 768] + o[tid + 768]) * inv_sq2 : 0.f;
  } else if (j < 60) {
    const int m = j - 30;
    const float* e = lmT + (size_t)(2 * m) * NROWS + base;
    const float* o = lmT + (size_t)(2 * m + 1) * NROWS + base;
    auto dl = [&](int t) -> float {
      int tp = (t + 1 > NFRAMES - 1) ? (NFRAMES - 1) : (t + 1);
      int tm = (t - 1 < 0) ? 0 : (t - 1);
      return ((e[tp] + o[tp]) - (e[tm] + o[tm])) * inv_sq2;
    };
    f0 = dl(tid);
    f1 = dl(tid + 256);
    f2 = dl(tid + 512);
    f3 = v3 ? dl(tid + 768) : 0.f;
  } else {
    const int m = j - 60;
    const float* e = lmT + (size_t)(2 * m) * NROWS + base;
    const float* o = lmT + (size_t)(2 * m + 1) * NROWS + base;
    f0 = (e[tid]       - o[tid])       * inv_sq2;
    f1 = (e[tid + 256] - o[tid + 256]) * inv_sq2;
    f2 = (e[tid + 512] - o[tid + 512]) * inv_sq2;
    f3 = v3 ? (e[tid + 768] - o[tid + 768]) * inv_sq2 : 0.f;
  }

  float s = f0 + f1 + f2 + f3;
  for (int o2 = 32; o2 > 0; o2 >>= 1) s += __shfl_xor(s, o2, 64);
  if ((tid & 63) == 0) red[tid >> 6] = s;
  __syncthreads();
  float mean = (red[0] + red[1] + red[2] + red[3]) / (float)NFRAMES;
  __syncthreads();

  float d0 = f0 - mean, d1 = f1 - mean, d2 = f2 - mean;
  float d3 = v3 ? (f3 - mean) : 0.f;
  float s2 = d0 * d0 + d1 * d1 + d2 * d2 + d3 * d3;
  for (int o2 = 32; o2 > 0; o2 >>= 1) s2 += __shfl_xor(s2, o2, 64);
  if ((tid & 63) == 0) red[tid >> 6] = s2;
  __syncthreads();
  float var = (red[0] + red[1] + red[2] + red[3]) / (float)(NFRAMES - 1);

  if (tid == 0) {
    out[b * 180 + j]      = mean;
    out[b * 180 + 90 + j] = sqrtf(var);
  }
}

extern "C" void kernel_launch(void* const* d_in, const int* in_sizes, int n_in,
                              void* d_out, int out_size, void* d_ws, size_t ws_size,
                              hipStream_t stream) {
  const float* wav  = (const float*)d_in[0];   // (16, 441000) f32
  const float* filt = (const float*)d_in[1];   // (60, 1025) f32
  float* out = (float*)d_out;                  // (16, 180) f32

  // ws: powrF bf16 [999 panels][16896], filtbF bf16 [4][16896], logmelT f32 [60][NROWS]
  unsigned char* ws = (unsigned char*)d_ws;
  __hip_bfloat16* powrF  = (__hip_bfloat16*)(ws);
  size_t off = (size_t)NPANEL * PANEL_ELEMS * 2;              // 33,758,208
  __hip_bfloat16* filtbF = (__hip_bfloat16*)(ws + off);
  off += (size_t)4 * PANEL_ELEMS * 2;                         // +135,168
  float* logmelT = (float*)(ws + off);                        // +3,836,160 => ~37.7 MB

  fft_pow_kernel<<<8064, 256, 0, stream>>>(wav, filt, powrF, filtbF);
  melgemm_kernel<<<(NPANEL + 1) / 2, 256, 0, stream>>>(powrF, filtbF, logmelT);
  stats_kernel<<<dim3(90, NBATCH), 256, 0, stream>>>(logmelT, out);
}

// Round 11
// 117.588 us; speedup vs baseline: 1.2884x; 1.0178x over previous
//
#include <hip/hip_runtime.h>
#include <hip/hip_bf16.h>
#include <math.h>

#define FRAME_LEN 882
#define FRAME_HOP 441
#define NFFT 2048
#define NFRAMES 999
#define NBATCH 16
#define NMEL 60
#define WAVE_LEN 441000
#define PRE_EMPH 0.97f
#define EPS 1e-10f
#define NROWS (NBATCH * NFRAMES)     // 15984 = 999 panels x 16 rows
#define NPANEL 999
#define KPAD 1056                    // 33*32
#define NKC 33
#define PANEL_ELEMS (NKC * 512)      // 16896 bf16 per panel (frag-linear)
#define PI_F 3.14159265358979323846f

// LDS vf2 index padding: +1 per 16
#define PADI(i) ((i) + ((i) >> 4))

// Frag-linear offset of (row m in panel, bin k)
__device__ __forceinline__ int frag_off(int m, int k) {
  return ((k >> 5) * 512) | (((k >> 3) & 3) * 128) | (m * 8) | (k & 7);
}

// Packed complex type
typedef float vf2 __attribute__((ext_vector_type(2)));
__device__ __forceinline__ vf2 mkv(float x, float y){ vf2 r; r.x = x; r.y = y; return r; }
__device__ __forceinline__ vf2 cmul(vf2 a, vf2 b){ return a.xx * b + mkv(-a.y, a.y) * b.yx; }
__device__ __forceinline__ vf2 rotni(vf2 z){ return mkv(z.y, -z.x); }  // z * (-i)

// Four consecutive DIF radix-2 stages (halves 8S,4S,2S,S), 16 elems/thread.
// Thread owns e_k = Q*16S + k*S + r. All twiddles from t1 = e^{-i*pi*r/(8S)}.
// (Ported verbatim from the R4-verified kernel, float2 -> vf2.)
__device__ __forceinline__ void dif_group16(vf2* x, vf2 t1, bool zerohi) {
  const vf2 C81 = mkv(0.9238795325f, -0.3826834324f);
  const vf2 C82 = mkv(0.7071067812f, -0.7071067812f);
  const vf2 C83 = mkv(0.3826834324f, -0.9238795325f);
  // stage half = 8S
  vf2 w0 = t1, w1 = cmul(t1, C81), w2 = cmul(t1, C82), w3 = cmul(t1, C83);
  vf2 ws1[8] = {w0, w1, w2, w3, rotni(w0), rotni(w1), rotni(w2), rotni(w3)};
  if (zerohi) {
    // x[8..15] known zero: x[k] stays, x[k+8] = x[k]*w
#pragma unroll
    for (int k = 0; k < 8; ++k) x[k + 8] = cmul(x[k], ws1[k]);
  } else {
#pragma unroll
    for (int k = 0; k < 8; ++k) {
      vf2 u = x[k], v = x[k + 8];
      x[k] = u + v;
      x[k + 8] = cmul(u - v, ws1[k]);
    }
  }
  // stage half = 4S
  vf2 t2 = cmul(t1, t1);
  vf2 v1 = cmul(t2, C82);
  vf2 ws2[4] = {t2, v1, rotni(t2), rotni(v1)};
#pragma unroll
  for (int h = 0; h < 2; ++h) {
#pragma unroll
    for (int k = 0; k < 4; ++k) {
      vf2 u = x[h*8 + k], v = x[h*8 + k + 4];
      x[h*8 + k] = u + v;
      x[h*8 + k + 4] = cmul(u - v, ws2[k]);
    }
  }
  // stage half = 2S
  vf2 t4 = cmul(t2, t2);
  vf2 t4r = rotni(t4);
#pragma unroll
  for (int h = 0; h < 4; ++h) {
    vf2 a = x[h*4 + 0], b = x[h*4 + 2];
    x[h*4 + 0] = a + b; x[h*4 + 2] = cmul(a - b, t4);
    a = x[h*4 + 1]; b = x[h*4 + 3];
    x[h*4 + 1] = a + b; x[h*4 + 3] = cmul(a - b, t4r);
  }
  // stage half = S
  vf2 t8 = cmul(t4, t4);
#pragma unroll
  for (int j = 0; j < 8; ++j) {
    vf2 a = x[2*j], b = x[2*j + 1];
    x[2*j] = a + b; x[2*j + 1] = cmul(a - b, t8);
  }
}

// Final 3 DIF stages (halves 4,2,1) on 8 consecutive elements (R4-verified).
__device__ __forceinline__ void dif8(vf2* y) {
  const vf2 c1 = mkv(0.7071067812f, -0.7071067812f);
  const vf2 c3 = mkv(-0.7071067812f, -0.7071067812f);
  vf2 u, v;
  u=y[0]; v=y[4]; y[0]=u+v; y[4]=u-v;
  u=y[1]; v=y[5]; y[1]=u+v; y[5]=cmul(u-v, c1);
  u=y[2]; v=y[6]; y[2]=u+v; y[6]=rotni(u-v);
  u=y[3]; v=y[7]; y[3]=u+v; y[7]=cmul(u-v, c3);
  u=y[0]; v=y[2]; y[0]=u+v; y[2]=u-v;
  u=y[1]; v=y[3]; y[1]=u+v; y[3]=rotni(u-v);
  u=y[4]; v=y[6]; y[4]=u+v; y[6]=u-v;
  u=y[5]; v=y[7]; y[5]=u+v; y[7]=rotni(u-v);
  u=y[0]; v=y[1]; y[0]=u+v; y[1]=u-v;
  u=y[2]; v=y[3]; y[2]=u+v; y[3]=u-v;
  u=y[4]; v=y[5]; y[4]=u+v; y[5]=u-v;
  u=y[6]; v=y[7]; y[6]=u+v; y[7]=u-v;
}

// Kernel 1 (merged): blocks [0,4000) each run TWO 2048-pt frame-pair FFTs
// side-by-side (threads 0-127 / 128-255, separate 17.4 KB LDS regions,
// shared barriers). Radix-16 blocking: stage plan 4+4+3, only 2 LDS
// exchange rounds -> 33% less LDS traffic than the radix-8 version.
// Blocks [4000,4064) do the filter->bf16 fragment conversion.
__global__ __launch_bounds__(256) void fft_pow_kernel(
    const float* __restrict__ wav, const float* __restrict__ filt,
    __hip_bfloat16* __restrict__ powrF, __hip_bfloat16* __restrict__ filtbF)
{
  __shared__ vf2 lds2[2][NFFT + (NFFT >> 4)];   // 2 x 17408 B = 34816 B
  const int id = blockIdx.x;

  if (id >= 4000) {
    // ---- filter conversion branch (64 blocks) ----
    const int mm = id - 4000;  // 0..63
    __hip_bfloat16* qp = filtbF + (size_t)(mm >> 4) * PANEL_ELEMS;
    const int m = mm & 15;
    for (int k = threadIdx.x; k < KPAD; k += 256) {
      float v = (mm < NMEL && k < 1025) ? filt[mm * 1025 + k] : 0.f;
      qp[frag_off(m, k)] = __float2bfloat16(v);
    }
    return;
  }

  const int t   = threadIdx.x;
  const int fid = t >> 7;            // which of the 2 FFTs in this block
  const int tt  = t & 127;           // thread id within the FFT (0..127)
  vf2* lds = lds2[fid];

  const int P  = id * 2 + fid;       // frame-pair index 0..7999
  const int b  = P & 15;
  const int t0 = 2 * (P >> 4), t1f = t0 + 1;
  const bool has1 = (t1f < NFRAMES);
  const float* w = wav + (size_t)b * WAVE_LEN;
  const int s0 = t0 * FRAME_HOP;
  int s1 = t1f * FRAME_HOP;
  if (s1 > WAVE_LEN - FRAME_LEN) s1 = WAVE_LEN - FRAME_LEN;

  vf2 x[16];
  // ---- load + pre-emphasis + Hamming: element i = k*128 + tt ----
  {
    float sB, cB, sD, cD;
    __sincosf(6.283185307179586f * (float)tt / 881.0f, &sB, &cB);
    __sincosf(6.283185307179586f * 128.0f / 881.0f, &sD, &cD);
    vf2 cur  = mkv(cB, sB);
    vf2 step = mkv(cD, sD);
#pragma unroll
    for (int k = 0; k < 7; ++k) {    // k>=7 -> i>=896 > 881 -> zero
      int i = k * 128 + tt;
      float v1 = 0.f, v2 = 0.f;
      if (i < FRAME_LEN) {
        float win = 0.54f - 0.46f * cur.x;
        int s = s0 + i;
        float e1 = (s > 0) ? (w[s] - PRE_EMPH * w[s - 1]) : w[s];
        v1 = e1 * win;
        int ss = s1 + i;             // ss >= 441 > 0 always
        v2 = (w[ss] - PRE_EMPH * w[ss - 1]) * win;
      }
      x[k] = mkv(v1, v2);
      cur = cmul(cur, step);
    }
#pragma unroll
    for (int k = 7; k < 16; ++k) x[k] = mkv(0.f, 0.f);
  }

  // ---- G0: halves 1024,512,256,128 (S=128, r=tt): t1 = e^{-i*pi*tt/1024}
  {
    float sA, cA;
    __sincosf(-PI_F * (float)tt / 1024.0f, &sA, &cA);
    dif_group16(x, mkv(cA, sA), true);   // x[8..15] zero on entry
  }
#pragma unroll
  for (int k = 0; k < 16; ++k) lds[PADI(k * 128 + tt)] = x[k];
  __syncthreads();

  // ---- G1: halves 64,32,16,8 (S=8): Q = tt>>3, r = tt&7; t1 = e^{-i*pi*r/64}
  {
    const int Q = tt >> 3, r = tt & 7;
    const int base = Q * 128 + r;
#pragma unroll
    for (int k = 0; k < 16; ++k) x[k] = lds[PADI(base + k * 8)];
    float sA, cA;
    __sincosf(-PI_F * (float)r / 64.0f, &sA, &cA);
    dif_group16(x, mkv(cA, sA), false);
    __syncthreads();
#pragma unroll
    for (int k = 0; k < 16; ++k) lds[PADI(base + k * 8)] = x[k];
  }
  __syncthreads();

  // ---- G2: halves 4,2,1 — two 8-point const-twiddle FFTs on consecutive runs
  {
    vf2 ya[8], yb[8];
#pragma unroll
    for (int j = 0; j < 8; ++j) {
      ya[j] = lds[PADI(16 * tt + j)];
      yb[j] = lds[PADI(16 * tt + 8 + j)];
    }
    dif8(ya);
    dif8(yb);
    __syncthreads();
#pragma unroll
    for (int j = 0; j < 8; ++j) {
      lds[PADI(16 * tt + j)] = ya[j];
      lds[PADI(16 * tt + 8 + j)] = yb[j];
    }
  }
  __syncthreads();

  // ---- power separation + bf16 store in FRAGMENT order ----
  const int r0g = b * NFRAMES + t0;
  const int r1g = r0g + 1;
  __hip_bfloat16* q0 = powrF + (size_t)(r0g >> 4) * PANEL_ELEMS;
  const int m0 = r0g & 15;
  __hip_bfloat16* q1 = powrF + (size_t)(r1g >> 4) * PANEL_ELEMS;
  const int m1 = r1g & 15;
#pragma unroll
  for (int c = 0; c < 8; ++c) {
    int f = c * 128 + tt;
    int j1 = (int)(__brev((unsigned)f) >> 21);
    int j2 = (int)(__brev((unsigned)((NFFT - f) & (NFFT - 1))) >> 21);
    vf2 z = lds[PADI(j1)];
    vf2 y = lds[PADI(j2)];
    float f1r = z.x + y.x, f1i = z.y - y.y;
    float f2r = z.y + y.y, f2i = y.x - z.x;
    float pw1 = 0.25f * (f1r * f1r + f1i * f1i);
    float pw2 = 0.25f * (f2r * f2r + f2i * f2i);
    q0[frag_off(m0, f)] = __float2bfloat16(pw1);
    if (has1) q1[frag_off(m1, f)] = __float2bfloat16(pw2);
  }
  if (tt == 0) {
    vf2 z = lds[PADI(1)];            // brev(1024) = 1; bin 1024 self-conjugate
    q0[frag_off(m0, 1024)] = __float2bfloat16(z.x * z.x);
    if (has1) q1[frag_off(m1, 1024)] = __float2bfloat16(z.y * z.y);
  }
  // zero the K pads (1025..KPAD-1)
  if (tt < KPAD - 1025) {
    int f = 1025 + tt;
    q0[frag_off(m0, f)] = __float2bfloat16(0.f);
    if (has1) q1[frag_off(m1, f)] = __float2bfloat16(0.f);
  }
}

// Kernel 2: mel GEMM, gather-free, 999 blocks (1 panel each, 4 blocks/CU for
// latency hiding), two independent K-chains (R8-verified structure).
typedef __attribute__((ext_vector_type(8))) short short8x;
typedef __attribute__((ext_vector_type(4))) float float4x;

__global__ __launch_bounds__(256) void melgemm_kernel(
    const __hip_bfloat16* __restrict__ powrF,
    const __hip_bfloat16* __restrict__ filtbF,
    float* __restrict__ logmelT)
{
  const int wave = threadIdx.x >> 6, lane = threadIdx.x & 63;
  const int p = blockIdx.x;                       // panel = rows [16p, 16p+16)
  const __hip_bfloat16* pA = powrF + (size_t)p * PANEL_ELEMS + lane * 8;
  const __hip_bfloat16* pB = filtbF + (size_t)wave * PANEL_ELEMS + lane * 8;

  float4x acc0 = {0.f, 0.f, 0.f, 0.f};
  float4x acc1 = {0.f, 0.f, 0.f, 0.f};
#pragma unroll 4
  for (int kc = 0; kc < 16; ++kc) {
    short8x a0 = *(const short8x*)(pA + kc * 512);
    short8x b0 = *(const short8x*)(pB + kc * 512);
    short8x a1 = *(const short8x*)(pA + (kc + 16) * 512);
    short8x b1 = *(const short8x*)(pB + (kc + 16) * 512);
    acc0 = __builtin_amdgcn_mfma_f32_16x16x32_bf16(a0, b0, acc0, 0, 0, 0);
    acc1 = __builtin_amdgcn_mfma_f32_16x16x32_bf16(a1, b1, acc1, 0, 0, 0);
  }
  {
    short8x a = *(const short8x*)(pA + 32 * 512);
    short8x bf = *(const short8x*)(pB + 32 * 512);
    acc0 = __builtin_amdgcn_mfma_f32_16x16x32_bf16(a, bf, acc0, 0, 0, 0);
  }

  // C/D layout: col = lane&15 (mel), row = (lane>>4)*4 + reg (panel row)
  const int mel = wave * 16 + (lane & 15);
  const int rsub = (lane >> 4) * 4;
  if (mel < NMEL) {
#pragma unroll
    for (int reg = 0; reg < 4; ++reg) {
      int row = p * 16 + rsub + reg;
      float vv = acc0[reg] + acc1[reg];
      logmelT[(size_t)mel * NROWS + row] = __logf(vv + EPS);
    }
  }
}

// Kernel 3: stats on transposed logmel (unchanged, R8-verified).
__global__ __launch_bounds__(256) void stats_kernel(
    const float* __restrict__ lmT, float* __restrict__ out)
{
  __shared__ float red[4];
  const int j   = blockIdx.x;   // 0..89
  const int b   = blockIdx.y;   // 0..15
  const int tid = threadIdx.x;
  const int base = b * NFRAMES;
  const float inv_sq2 = 0.7071067811865475f;
  const bool v3 = (tid < NFRAMES - 768);

  float f0, f1, f2, f3;
  if (j < 30) {
    const float* e = lmT + (size_t)(2 * j) * NROWS + base;
    const float* o = lmT + (size_t)(2 * j + 1) * NROWS + base;
    f0 = (e[tid]       + o[tid])       * inv_sq2;
    f1 = (e[tid + 256] + o[tid + 256]) * inv_sq2;
    f2 = (e[tid + 512] + o[tid + 512]) * inv_sq2;
    f3 = v3 ? (e[tid + 768] + o[tid + 768]) * inv_sq2 : 0.f;
  } else if (j < 60) {
    const int m = j - 30;
    const float* e = lmT + (size_t)(2 * m) * NROWS + base;
    const float* o = lmT + (size_t)(2 * m + 1) * NROWS + base;
    auto dl = [&](int t) -> float {
      int tp = (t + 1 > NFRAMES - 1) ? (NFRAMES - 1) : (t + 1);
      int tm = (t - 1 < 0) ? 0 : (t - 1);
      return ((e[tp] + o[tp]) - (e[tm] + o[tm])) * inv_sq2;
    };
    f0 = dl(tid);
    f1 = dl(tid + 256);
    f2 = dl(tid + 512);
    f3 = v3 ? dl(tid + 768) : 0.f;
  } else {
    const int m = j - 60;
    const float* e = lmT + (size_t)(2 * m) * NROWS + base;
    const float* o = lmT + (size_t)(2 * m + 1) * NROWS + base;
    f0 = (e[tid]       - o[tid])       * inv_sq2;
    f1 = (e[tid + 256] - o[tid + 256]) * inv_sq2;
    f2 = (e[tid + 512] - o[tid + 512]) * inv_sq2;
    f3 = v3 ? (e[tid + 768] - o[tid + 768]) * inv_sq2 : 0.f;
  }

  float s = f0 + f1 + f2 + f3;
  for (int o2 = 32; o2 > 0; o2 >>= 1) s += __shfl_xor(s, o2, 64);
  if ((tid & 63) == 0) red[tid >> 6] = s;
  __syncthreads();
  float mean = (red[0] + red[1] + red[2] + red[3]) / (float)NFRAMES;
  __syncthreads();

  float d0 = f0 - mean, d1 = f1 - mean, d2 = f2 - mean;
  float d3 = v3 ? (f3 - mean) : 0.f;
  float s2 = d0 * d0 + d1 * d1 + d2 * d2 + d3 * d3;
  for (int o2 = 32; o2 > 0; o2 >>= 1) s2 += __shfl_xor(s2, o2, 64);
  if ((tid & 63) == 0) red[tid >> 6] = s2;
  __syncthreads();
  float var = (red[0] + red[1] + red[2] + red[3]) / (float)(NFRAMES - 1);

  if (tid == 0) {
    out[b * 180 + j]      = mean;
    out[b * 180 + 90 + j] = sqrtf(var);
  }
}

extern "C" void kernel_launch(void* const* d_in, const int* in_sizes, int n_in,
                              void* d_out, int out_size, void* d_ws, size_t ws_size,
                              hipStream_t stream) {
  const float* wav  = (const float*)d_in[0];   // (16, 441000) f32
  const float* filt = (const float*)d_in[1];   // (60, 1025) f32
  float* out = (float*)d_out;                  // (16, 180) f32

  // ws: powrF bf16 [999 panels][16896], filtbF bf16 [4][16896], logmelT f32 [60][NROWS]
  unsigned char* ws = (unsigned char*)d_ws;
  __hip_bfloat16* powrF  = (__hip_bfloat16*)(ws);
  size_t off = (size_t)NPANEL * PANEL_ELEMS * 2;              // 33,758,208
  __hip_bfloat16* filtbF = (__hip_bfloat16*)(ws + off);
  off += (size_t)4 * PANEL_ELEMS * 2;                         // +135,168
  float* logmelT = (float*)(ws + off);                        // +3,836,160 => ~37.7 MB

  fft_pow_kernel<<<4064, 256, 0, stream>>>(wav, filt, powrF, filtbF);
  melgemm_kernel<<<NPANEL, 256, 0, stream>>>(powrF, filtbF, logmelT);
  stats_kernel<<<dim3(90, NBATCH), 256, 0, stream>>>(logmelT, out);
}